// Round 2
// baseline (167.342 us; speedup 1.0000x reference)
//
#include <hip/hip_runtime.h>

// InfoNCE-on-image-norms, fused single kernel:
//   Stage 1: 128 images x 21 chunks = 2688 blocks x 256 thr, each thread
//            7 coalesced float4 loads -> sum of squares -> block partial.
//   Stage 2: last finishing block (atomic-counter pattern) computes the
//            128 norms, mu/std (ddof=0), exp/log loss in double precision.
// Cross-XCD visibility: partials stored with agent-scope atomic stores,
// release/acquire ordering around an agent-scope counter.

#define IMG_ELEMS   150528          // 3*224*224
#define VEC_PER_IMG 37632           // IMG_ELEMS/4
#define CHUNKS      21
#define VEC_PER_CHK 1792            // 37632/21
#define ITERS       7               // 1792/256
#define NBLOCKS     (128 * CHUNKS)  // 2688
#define TEMPERATURE 0.7

__global__ __launch_bounds__(256) void infonce_fused(const float* __restrict__ pos,
                                                     const float* __restrict__ neg,
                                                     unsigned int* __restrict__ counter,
                                                     float* __restrict__ partials,
                                                     float* __restrict__ out) {
    const int bid   = blockIdx.x;          // 0..2687
    const int img   = bid / CHUNKS;        // 0..127
    const int chunk = bid % CHUNKS;        // 0..20

    const float* base = (img < 64) ? (pos + (size_t)img * IMG_ELEMS)
                                   : (neg + (size_t)(img - 64) * IMG_ELEMS);
    const float4* src = (const float4*)base;

    int idx = chunk * VEC_PER_CHK + threadIdx.x;
    float acc = 0.0f;
#pragma unroll
    for (int i = 0; i < ITERS; ++i) {
        float4 v = src[idx + i * 256];
        acc += v.x * v.x + v.y * v.y + v.z * v.z + v.w * v.w;
    }

    // 64-lane wave reduction
#pragma unroll
    for (int off = 32; off > 0; off >>= 1)
        acc += __shfl_down(acc, off, 64);

    __shared__ float lds[4];
    __shared__ int   last_flag;
    const int wave = threadIdx.x >> 6;
    const int lane = threadIdx.x & 63;
    if (lane == 0) lds[wave] = acc;
    __syncthreads();

    if (threadIdx.x == 0) {
        float p = lds[0] + lds[1] + lds[2] + lds[3];
        // device-scope visible store of the partial
        __hip_atomic_store(&partials[bid], p, __ATOMIC_RELAXED, __HIP_MEMORY_SCOPE_AGENT);
        __threadfence();  // release partials before the counter bump
        unsigned int old = __hip_atomic_fetch_add(counter, 1u, __ATOMIC_ACQ_REL,
                                                  __HIP_MEMORY_SCOPE_AGENT);
        last_flag = (old == NBLOCKS - 1) ? 1 : 0;
    }
    __syncthreads();
    if (!last_flag) return;

    // ---- Stage 2: only the last block reaches here (all 256 threads) ----
    __threadfence();  // acquire: all partials visible

    const int t = threadIdx.x;             // threads 0..127 own image t
    double norm = 0.0;
    if (t < 128) {
        float s = 0.0f;
#pragma unroll
        for (int i = 0; i < CHUNKS; ++i)
            s += __hip_atomic_load(&partials[t * CHUNKS + i], __ATOMIC_RELAXED,
                                   __HIP_MEMORY_SCOPE_AGENT);
        norm = sqrt((double)s);
    }

    // mean / E[x^2] over the 128 norms (waves 0 and 1; waves 2,3 contribute 0)
    double sum = norm, sumsq = norm * norm;
#pragma unroll
    for (int off = 32; off > 0; off >>= 1) {
        sum   += __shfl_down(sum,   off, 64);
        sumsq += __shfl_down(sumsq, off, 64);
    }
    __shared__ double red[8];
    if (lane == 0) { red[wave * 2] = sum; red[wave * 2 + 1] = sumsq; }
    __syncthreads();

    const double tot   = red[0] + red[2];  // waves 2,3 are zero anyway
    const double totsq = red[1] + red[3];
    const double mu    = tot / 128.0;
    double var         = totsq / 128.0 - mu * mu;
    if (var < 0.0) var = 0.0;
    const double denom = sqrt(var) * TEMPERATURE;

    double e = (t < 128) ? exp((norm - mu) / denom) : 0.0;

    // per-wave sums: wave0 -> pos_sim, wave1 -> neg_sim
#pragma unroll
    for (int off = 32; off > 0; off >>= 1)
        e += __shfl_down(e, off, 64);

    __shared__ double sims[4];
    if (lane == 0) sims[wave] = e;
    __syncthreads();

    if (t == 0) {
        const double ps = sims[0];
        const double ns = sims[1];
        out[0] = (float)(-log(ps / (ps + ns)));
    }
}

extern "C" void kernel_launch(void* const* d_in, const int* in_sizes, int n_in,
                              void* d_out, int out_size, void* d_ws, size_t ws_size,
                              hipStream_t stream) {
    const float* pos = (const float*)d_in[0];
    const float* neg = (const float*)d_in[1];

    unsigned int* counter = (unsigned int*)d_ws;                 // 4 bytes
    float* partials       = (float*)((char*)d_ws + 128);         // 2688 floats
    float* out            = (float*)d_out;

    hipMemsetAsync(counter, 0, sizeof(unsigned int), stream);    // capture-legal memset node
    infonce_fused<<<NBLOCKS, 256, 0, stream>>>(pos, neg, counter, partials, out);
}

// Round 3
// 19.238 us; speedup vs baseline: 8.6984x; 8.6984x over previous
//
#include <hip/hip_runtime.h>

// InfoNCE-on-image-norms, two-kernel (fence-free) version:
//   Stage 1: 128 images x 21 chunks = 2688 blocks x 256 thr; each thread
//            7 coalesced float4 loads -> sum of squares; wave shuffle
//            reduce + LDS -> one float partial per block (plain store).
//   Stage 2: 1 block x 128 thr; thread t sums image t's 21 partials,
//            sqrt -> norm; mu/std (ddof=0) + exp/log loss in double.
// Kernel boundary provides cross-XCD visibility -- no fences, no atomics
// (R2 showed per-block agent-scope fences cost ~200us in L2 maintenance).

#define IMG_ELEMS   150528          // 3*224*224
#define VEC_PER_IMG 37632           // IMG_ELEMS/4
#define CHUNKS      21
#define VEC_PER_CHK 1792            // 37632/21
#define ITERS       7               // 1792/256
#define TEMPERATURE 0.7

__global__ __launch_bounds__(256) void sumsq_kernel(const float* __restrict__ pos,
                                                    const float* __restrict__ neg,
                                                    float* __restrict__ partials) {
    const int bid   = blockIdx.x;          // 0..2687
    const int img   = bid / CHUNKS;        // 0..127
    const int chunk = bid % CHUNKS;        // 0..20

    const float* base = (img < 64) ? (pos + (size_t)img * IMG_ELEMS)
                                   : (neg + (size_t)(img - 64) * IMG_ELEMS);
    const float4* src = (const float4*)base;

    int idx = chunk * VEC_PER_CHK + threadIdx.x;
    float acc = 0.0f;
#pragma unroll
    for (int i = 0; i < ITERS; ++i) {
        float4 v = src[idx + i * 256];
        acc += v.x * v.x + v.y * v.y + v.z * v.z + v.w * v.w;
    }

    // 64-lane wave reduction
#pragma unroll
    for (int off = 32; off > 0; off >>= 1)
        acc += __shfl_down(acc, off, 64);

    __shared__ float lds[4];
    const int wave = threadIdx.x >> 6;
    const int lane = threadIdx.x & 63;
    if (lane == 0) lds[wave] = acc;
    __syncthreads();
    if (threadIdx.x == 0)
        partials[bid] = lds[0] + lds[1] + lds[2] + lds[3];
}

__global__ __launch_bounds__(128) void loss_kernel(const float* __restrict__ partials,
                                                   float* __restrict__ out) {
    const int t = threadIdx.x;             // 0..127 ; wave0 = pos, wave1 = neg
    const int wave = t >> 6;
    const int lane = t & 63;

    float s = 0.0f;
#pragma unroll
    for (int i = 0; i < CHUNKS; ++i) s += partials[t * CHUNKS + i];
    const double norm = sqrt((double)s);

    // mean / E[x^2] over all 128 norms (double)
    double sum = norm, sumsq = norm * norm;
#pragma unroll
    for (int off = 32; off > 0; off >>= 1) {
        sum   += __shfl_down(sum,   off, 64);
        sumsq += __shfl_down(sumsq, off, 64);
    }
    __shared__ double red[4];
    if (lane == 0) { red[wave * 2] = sum; red[wave * 2 + 1] = sumsq; }
    __syncthreads();

    const double tot   = red[0] + red[2];
    const double totsq = red[1] + red[3];
    const double mu    = tot / 128.0;
    double var         = totsq / 128.0 - mu * mu;
    if (var < 0.0) var = 0.0;
    const double denom = sqrt(var) * TEMPERATURE;

    const double e = exp((norm - mu) / denom);

    // per-wave sum: wave0 -> pos_sim, wave1 -> neg_sim
    double esum = e;
#pragma unroll
    for (int off = 32; off > 0; off >>= 1)
        esum += __shfl_down(esum, off, 64);

    __shared__ double sims[2];
    if (lane == 0) sims[wave] = esum;
    __syncthreads();

    if (t == 0) {
        const double ps = sims[0];
        const double ns = sims[1];
        out[0] = (float)(-log(ps / (ps + ns)));
    }
}

extern "C" void kernel_launch(void* const* d_in, const int* in_sizes, int n_in,
                              void* d_out, int out_size, void* d_ws, size_t ws_size,
                              hipStream_t stream) {
    const float* pos = (const float*)d_in[0];
    const float* neg = (const float*)d_in[1];
    float* partials  = (float*)d_ws;        // 2688 floats
    float* out       = (float*)d_out;       // 1 float

    sumsq_kernel<<<128 * CHUNKS, 256, 0, stream>>>(pos, neg, partials);
    loss_kernel<<<1, 128, 0, stream>>>(partials, out);
}